// Round 5
// baseline (175.705 us; speedup 1.0000x reference)
//
#include <hip/hip_runtime.h>

// MiddleDecoder fused MLP, MFMA edition (32x32x16 bf16).
// Kernel T: weight transposes -> ws (bf16), batch output.
// Kernel S: S = b1 + feat@W1[3:], rel = pf@Wn + bn, out0.   (MFMA)
// Kernel M: h1 build in-reg -> swapped layer2 MFMA -> shfl half-swap -> layer3 MFMA.
// R4: passed, 160us. kM 135us: VALUBusy 42 + MfmaUtil 18, occ 19.7% (reg-capped),
//     96 global W1 loads/g unhidden.
// R5: kM -> 512thr/8 waves, 2 points per g (acc 128->64 regs), W1 rows 0-2 in LDS
//     (f32, 3KB), launch_bounds(512,3). Target 16 waves/CU, VALUBusy ~70%.

#define NPTS 50000
#define MROWS (NPTS * 16)
#define OFF_FC3 ((size_t)MROWS * 3)
#define OFF_BATCH ((size_t)MROWS * 35)

typedef unsigned int uint_;
typedef unsigned short ushort_;
typedef __attribute__((ext_vector_type(8))) short bf16x8s;
typedef __attribute__((ext_vector_type(16))) float f32x16;

#define MFMA(a, b, c) __builtin_amdgcn_mfma_f32_32x32x16_bf16(a, b, c, 0, 0, 0)
#define CROW(r, h) (((r) & 3) + 8 * ((r) >> 2) + 4 * (h))

// ws layout (ushort offsets): W2T[128][256] @0 | W3T[32][128] @32768 |
// W1pT[256][128] @36864 | WnT[64][32] @69632 | S[50000][256] @71680 | rel f32 after.
#define WS_W2T 0
#define WS_W3T 32768
#define WS_W1PT 36864
#define WS_WNT 69632
#define WS_S 71680
#define WS_REL_BYTES 25743360

__device__ __forceinline__ float bl(uint_ u) { return __uint_as_float(u << 16); }
__device__ __forceinline__ float bh(uint_ u) { return __uint_as_float(u & 0xffff0000u); }
__device__ __forceinline__ ushort_ f2b(float f) {  // RNE f32->bf16
  uint_ u = __float_as_uint(f);
  u += 0x7fffu + ((u >> 16) & 1u);
  return (ushort_)(u >> 16);
}
__device__ __forceinline__ uint_ cvtpk(float lo, float hi) {
  uint_ r;
  asm("v_cvt_pk_bf16_f32 %0, %1, %2" : "=v"(r) : "v"(lo), "v"(hi));
  return r;
}
__device__ __forceinline__ float relu_(float x) { return fmaxf(x, 0.f); }

template<bool F32>
__device__ __forceinline__ float ldv(const void* p, int i) {
  if (F32) return ((const float*)p)[i];
  return bl((uint_)((const ushort_*)p)[i]);
}

struct F8 { float v[8]; };
template<bool F32>
__device__ __forceinline__ F8 ld8(const void* p, int idx) {  // idx multiple of 8
  F8 r;
  if (F32) {
    float4 a = *(const float4*)((const float*)p + idx);
    float4 b = *(const float4*)((const float*)p + idx + 4);
    r.v[0] = a.x; r.v[1] = a.y; r.v[2] = a.z; r.v[3] = a.w;
    r.v[4] = b.x; r.v[5] = b.y; r.v[6] = b.z; r.v[7] = b.w;
  } else {
    uint4 u = *(const uint4*)((const ushort_*)p + idx);
    r.v[0] = bl(u.x); r.v[1] = bh(u.x); r.v[2] = bl(u.y); r.v[3] = bh(u.y);
    r.v[4] = bl(u.z); r.v[5] = bh(u.z); r.v[6] = bl(u.w); r.v[7] = bh(u.w);
  }
  return r;
}
__device__ __forceinline__ F8 ld8lds(const float* p) {  // 32B-aligned LDS read
  F8 r;
  float4 a = *(const float4*)p;
  float4 b = *(const float4*)(p + 4);
  r.v[0] = a.x; r.v[1] = a.y; r.v[2] = a.z; r.v[3] = a.w;
  r.v[4] = b.x; r.v[5] = b.y; r.v[6] = b.z; r.v[7] = b.w;
  return r;
}
template<bool F32>
__device__ __forceinline__ void ld4f(const void* p, int idx, float* o) {  // idx mult of 4
  if (F32) {
    float4 v = *(const float4*)((const float*)p + idx);
    o[0] = v.x; o[1] = v.y; o[2] = v.z; o[3] = v.w;
  } else {
    uint2 v = *(const uint2*)((const ushort_*)p + idx);
    o[0] = bl(v.x); o[1] = bh(v.x); o[2] = bl(v.y); o[3] = bh(v.y);
  }
}

union FragU { uint_ u[4]; uint4 q; bf16x8s v; };
__device__ __forceinline__ bf16x8s pack8(const F8& f) {
  FragU o;
  #pragma unroll
  for (int j = 0; j < 4; ++j) o.u[j] = cvtpk(f.v[2 * j], f.v[2 * j + 1]);
  return o.v;
}

// true -> f32 inputs. bf16 N(0,1): all 32 u16 have plausible exponent; f32 ~58%.
__device__ __forceinline__ bool sniff_f32(const void* feats) {
  const ushort_* u = (const ushort_*)feats;
  int pass = 0;
  #pragma unroll 8
  for (int m = 0; m < 32; ++m) {
    int ex = (u[m] >> 7) & 0xff;
    pass += (ex >= 100 && ex <= 140) ? 1 : 0;
  }
  return pass < 28;
}

// ---------------- Kernel T: transposes + batch ----------------
__global__ void __launch_bounds__(256)
kT(const void* features, const void* batch, const void* W1, const void* Wn,
   const void* W2, const void* W3, ushort_* wsu, float* out) {
  bool f32 = sniff_f32(features);
  const uint_* bu = (const uint_*)batch;
  int nz = 0;
  #pragma unroll
  for (int m = 0; m < 16; ++m) nz += (bu[49999 - 2 * m] != 0u) ? 1 : 0;
  bool i64 = (nz == 0);

  const int total = 32768 + 32768 + 4096 + 2048 + 800000;
  for (int i = blockIdx.x * 256 + threadIdx.x; i < total; i += gridDim.x * 256) {
    if (i < 32768) {                       // W1pT[n*128+k] = W1[(3+k)*256+n]
      int n = i & 255, k = i >> 8;
      wsu[WS_W1PT + n * 128 + k] = f32 ? f2b(((const float*)W1)[(3 + k) * 256 + n])
                                       : ((const ushort_*)W1)[(3 + k) * 256 + n];
    } else if (i < 65536) {                // W2T[n*256+k] = W2[k*128+n]
      int i2 = i - 32768, n = i2 & 127, k = i2 >> 7;
      wsu[WS_W2T + n * 256 + k] = f32 ? f2b(((const float*)W2)[k * 128 + n])
                                      : ((const ushort_*)W2)[k * 128 + n];
    } else if (i < 69632) {                // W3T[n*128+k] = W3[k*32+n]
      int i3 = i - 65536, n = i3 & 31, k = i3 >> 5;
      wsu[WS_W3T + n * 128 + k] = f32 ? f2b(((const float*)W3)[k * 32 + n])
                                      : ((const ushort_*)W3)[k * 32 + n];
    } else if (i < 71680) {                // WnT[n*32+k] = Wn[k*48+n], rows>=48 zero
      int i4 = i - 69632, n = i4 >> 5, k = i4 & 31;
      ushort_ v = 0;
      if (n < 48) v = f32 ? f2b(((const float*)Wn)[k * 48 + n])
                          : ((const ushort_*)Wn)[k * 48 + n];
      wsu[WS_WNT + n * 32 + k] = v;
    } else {                               // batch output
      int g = i - 71680;
      int idx = g >> 4;
      int v = i64 ? (int)bu[2 * idx] : ((const int*)batch)[idx];
      out[OFF_BATCH + (size_t)g] = (float)v;
    }
  }
}

// ---------------- Kernel S: S, rel, out0 ----------------
template<bool F32>
__device__ void runS(const void* points, const void* features, const void* bn,
                     const void* b1, ushort_* wsu, float* out,
                     ushort_* w1pt, ushort_* feats) {
  const ushort_* W1pT_ws = wsu + WS_W1PT;
  const ushort_* WnT_ws = wsu + WS_WNT;
  ushort_* S_ws = wsu + WS_S;
  float* rel_ws = (float*)((char*)wsu + WS_REL_BYTES);
  const int tid = threadIdx.x;

  for (int c = tid; c < 4096; c += 256) {  // stage W1pT (256 rows x 256B) swizzled
    int n = c >> 4, s = c & 15;
    uint4 src = *(const uint4*)(W1pT_ws + c * 8);
    *(uint4*)((char*)w1pt + n * 256 + ((s * 16) ^ ((n & 7) << 4))) = src;
  }

  const int w = tid >> 6, lane = tid & 63, l31 = lane & 31, h = lane >> 5, h8 = h * 8;
  const int mt = w & 1, ctb = (w >> 1) * 4, ctr = w >> 1;

  for (int tile = blockIdx.x; tile < 782; tile += gridDim.x) {
    const int pbase = tile * 64;
    for (int c = tid; c < 2048; c += 256) {  // stage feat cols 32..160 bf16 swizzled
      int row = c >> 5, c4 = c & 31;
      int p = pbase + row;
      uint2 d = {0u, 0u};
      if (p < NPTS) {
        if (F32) {
          float4 v = *(const float4*)((const float*)features + p * 160 + 32 + c4 * 4);
          d.x = cvtpk(v.x, v.y); d.y = cvtpk(v.z, v.w);
        } else {
          d = *(const uint2*)((const ushort_*)features + p * 160 + 32 + c4 * 4);
        }
      }
      *(uint2*)((char*)feats + row * 256 + ((c4 * 8) ^ ((row & 7) << 4))) = d;
    }
    __syncthreads();

    // ---- S GEMM: A = feat rows, B = W1p ----
    bf16x8s af[8];
    #pragma unroll
    for (int ks = 0; ks < 8; ++ks) {
      int row = mt * 32 + l31;
      af[ks] = *(const bf16x8s*)((const char*)feats + row * 256 +
                                 (((ks * 16 + h8) * 2) ^ ((row & 7) << 4)));
    }
    #pragma unroll
    for (int ci = 0; ci < 4; ++ci) {
      int ct = ctb + ci;
      float b1v = ldv<F32>(b1, ct * 32 + l31);
      f32x16 acc;
      #pragma unroll
      for (int r = 0; r < 16; ++r) acc[r] = b1v;
      #pragma unroll
      for (int ks = 0; ks < 8; ++ks) {
        int n = ct * 32 + l31;
        bf16x8s bf = *(const bf16x8s*)((const char*)w1pt + n * 256 +
                                       (((ks * 16 + h8) * 2) ^ ((n & 7) << 4)));
        acc = MFMA(af[ks], bf, acc);
      }
      #pragma unroll
      for (int r = 0; r < 16; ++r) {
        int p = pbase + mt * 32 + CROW(r, h);
        if (p < NPTS) S_ws[p * 256 + ct * 32 + l31] = f2b(acc[r]);
      }
    }

    // ---- rel GEMM: A = pf (feat cols 0..32), B = Wn ----
    {
      int pm = pbase + mt * 32 + l31;
      pm = pm < NPTS ? pm : NPTS - 1;
      bf16x8s ar[2];
      #pragma unroll
      for (int ks = 0; ks < 2; ++ks) {
        F8 v = ld8<F32>(features, pm * 160 + ks * 16 + h8);
        ar[ks] = pack8(v);
      }
      f32x16 acc;
      #pragma unroll
      for (int r = 0; r < 16; ++r) acc[r] = 0.f;
      #pragma unroll
      for (int ks = 0; ks < 2; ++ks) {
        int n = ctr * 32 + l31;
        FragU bw;
        bw.q = *(const uint4*)(WnT_ws + n * 32 + ks * 16 + h8);
        acc = MFMA(ar[ks], bw.v, acc);
      }
      int j = ctr * 32 + l31;
      if (j < 48) {
        float bnv = ldv<F32>(bn, j);
        int c = j - (j / 3) * 3;
        #pragma unroll
        for (int r = 0; r < 16; ++r) {
          int p = pbase + mt * 32 + CROW(r, h);
          if (p < NPTS) {
            float rv = acc[r] + bnv;
            rel_ws[p * 48 + j] = rv;
            out[(size_t)p * 48 + j] = ldv<F32>(points, p * 3 + c) + 0.25f * rv;
          }
        }
      }
    }
    __syncthreads();
  }
}

__global__ void __launch_bounds__(256, 2)
kS(const void* points, const void* features, const void* bn, const void* b1,
   ushort_* wsu, float* out) {
  __shared__ ushort_ w1pt[32768];  // 64KB
  __shared__ ushort_ feats[8192];  // 16KB
  if (sniff_f32(features))
    runS<true>(points, features, bn, b1, wsu, out, w1pt, feats);
  else
    runS<false>(points, features, bn, b1, wsu, out, w1pt, feats);
}

// ---------------- Kernel M: h1 build + layer2 + layer3 ----------------
__device__ __forceinline__ bf16x8s build8(uint4 s, const F8& wx, const F8& wy,
                                          const F8& wz, float r0, float r1, float r2) {
  uint_ su[4] = {s.x, s.y, s.z, s.w};
  F8 f;
  #pragma unroll
  for (int j = 0; j < 8; ++j) {
    uint_ u = su[j >> 1];
    float sv = (j & 1) ? bh(u) : bl(u);
    f.v[j] = relu_(sv + r0 * wx.v[j] + r1 * wy.v[j] + r2 * wz.v[j]);
  }
  return pack8(f);
}

__device__ __forceinline__ bf16x8s assemble(const f32x16& a, int base, bool lo) {
  float e[8];
  #pragma unroll
  for (int j = 0; j < 8; ++j) e[j] = relu_(a[base + j]);
  uint_ A0 = cvtpk(e[0], e[1]), A1 = cvtpk(e[2], e[3]);
  uint_ B0 = cvtpk(e[4], e[5]), B1 = cvtpk(e[6], e[7]);
  uint_ sA0 = (uint_)__shfl_xor((int)A0, 32);
  uint_ sA1 = (uint_)__shfl_xor((int)A1, 32);
  uint_ sB0 = (uint_)__shfl_xor((int)B0, 32);
  uint_ sB1 = (uint_)__shfl_xor((int)B1, 32);
  FragU o;
  o.u[0] = lo ? A0 : sB0;
  o.u[1] = lo ? A1 : sB1;
  o.u[2] = lo ? sA0 : B0;
  o.u[3] = lo ? sA1 : B1;
  return o.v;
}

template<bool F32>
__device__ void runM(const void* W1, const void* b2, const void* b3,
                     const ushort_* wsu, float* out,
                     ushort_* w2t, ushort_* w3t, float* w1f) {
  const ushort_* S_ws = wsu + WS_S;
  const float* rel_ws = (const float*)((const char*)wsu + WS_REL_BYTES);
  const int tid = threadIdx.x;

  // stage W2T (128 rows x 512B: n=c>>5, s=c&31) + W3T (32 x 256B) + W1 rows 0-2 f32
  for (int c = tid; c < 4608; c += 512) {
    if (c < 4096) {
      int n = c >> 5, s = c & 31;
      uint4 src = *(const uint4*)(wsu + WS_W2T + c * 8);
      *(uint4*)((char*)w2t + n * 512 + ((s * 16) ^ ((n & 7) << 4))) = src;
    } else {
      int c2 = c - 4096, n = c2 >> 4, s = c2 & 15;
      uint4 src = *(const uint4*)(wsu + WS_W3T + c2 * 8);
      *(uint4*)((char*)w3t + n * 256 + ((s * 16) ^ ((n & 7) << 4))) = src;
    }
  }
  for (int c = tid; c < 768; c += 512) w1f[c] = ldv<F32>(W1, c);
  __syncthreads();

  const int w = tid >> 6, lane = tid & 63, l31 = lane & 31, h = lane >> 5;
  const int h8 = h * 8, nb = lane & 15;
  const bool lo = lane < 32;
  const int slot = blockIdx.x * 8 + w;

  for (int g = slot; g < 25000; g += 4096) {
    const int p0 = g * 2;
    const int p = p0 + (l31 >> 4);
    const float r0 = rel_ws[p * 48 + nb * 3 + 0];
    const float r1 = rel_ws[p * 48 + nb * 3 + 1];
    const float r2 = rel_ws[p * 48 + nb * 3 + 2];

    f32x16 acc[4];
    #pragma unroll
    for (int mt = 0; mt < 4; ++mt) {
      #pragma unroll
      for (int q = 0; q < 4; ++q) {
        float t[4];
        ld4f<F32>(b2, mt * 32 + q * 8 + 4 * h, t);
        #pragma unroll
        for (int s = 0; s < 4; ++s) acc[mt][4 * q + s] = t[s];
      }
    }

    #pragma unroll 2
    for (int ks = 0; ks < 16; ++ks) {
      const int koff = ks * 16 + h8;
      F8 wx = ld8lds(w1f + koff);
      F8 wy = ld8lds(w1f + 256 + koff);
      F8 wz = ld8lds(w1f + 512 + koff);
      uint4 sa = *(const uint4*)(S_ws + p * 256 + koff);
      bf16x8s hh = build8(sa, wx, wy, wz, r0, r1, r2);
      const int kb = koff * 2;
      #pragma unroll
      for (int mt = 0; mt < 4; ++mt) {
        int n = mt * 32 + l31;
        bf16x8s af = *(const bf16x8s*)((const char*)w2t + n * 512 +
                                       (kb ^ ((n & 7) << 4)));
        acc[mt] = MFMA(af, hh, acc[mt]);
      }
    }

    // layer3: A = W3T (LDS), B = half-swapped relu(h2) from acc regs
    f32x16 o3;
    #pragma unroll
    for (int q = 0; q < 4; ++q) {
      float t[4];
      ld4f<F32>(b3, q * 8 + 4 * h, t);
      #pragma unroll
      for (int s = 0; s < 4; ++s) o3[4 * q + s] = t[s];
    }
    #pragma unroll
    for (int ks3 = 0; ks3 < 8; ++ks3) {
      int kb = (ks3 * 16 + h8) * 2;
      bf16x8s a3 = *(const bf16x8s*)((const char*)w3t + l31 * 256 +
                                     (kb ^ ((l31 & 7) << 4)));
      bf16x8s B3 = assemble(acc[ks3 >> 1], (ks3 & 1) * 8, lo);
      o3 = MFMA(a3, B3, o3);
    }

    const size_t row = (size_t)p0 * 16 + l31;
    #pragma unroll
    for (int q = 0; q < 4; ++q) {
      float4 v = {relu_(o3[4 * q]), relu_(o3[4 * q + 1]),
                  relu_(o3[4 * q + 2]), relu_(o3[4 * q + 3])};
      *(float4*)(out + OFF_FC3 + row * 32 + q * 8 + 4 * h) = v;
    }
  }
}

__global__ void __launch_bounds__(512, 3)
kM(const void* features, const void* W1, const void* b2, const void* b3,
   const ushort_* wsu, float* out) {
  __shared__ ushort_ w2t[32768];  // 64KB swizzled
  __shared__ ushort_ w3t[4096];   // 8KB swizzled
  __shared__ float w1f[768];      // 3KB W1 rows 0-2
  if (sniff_f32(features))
    runM<true>(W1, b2, b3, wsu, out, w2t, w3t, w1f);
  else
    runM<false>(W1, b2, b3, wsu, out, w2t, w3t, w1f);
}

extern "C" void kernel_launch(void* const* d_in, const int* in_sizes, int n_in,
                              void* d_out, int out_size, void* d_ws, size_t ws_size,
                              hipStream_t stream) {
  const void* points   = d_in[0];
  const void* features = d_in[1];
  const void* batch    = d_in[2];
  const void* Wn = d_in[3];  const void* bn = d_in[4];
  const void* W1 = d_in[5];  const void* b1 = d_in[6];
  const void* W2 = d_in[7];  const void* b2 = d_in[8];
  const void* W3 = d_in[9];  const void* b3 = d_in[10];
  float* out = (float*)d_out;
  ushort_* wsu = (ushort_*)d_ws;

  hipLaunchKernelGGL(kT, dim3(512), dim3(256), 0, stream,
                     features, batch, W1, Wn, W2, W3, wsu, out);
  hipLaunchKernelGGL(kS, dim3(782), dim3(256), 0, stream,
                     points, features, bn, b1, wsu, out);
  hipLaunchKernelGGL(kM, dim3(512), dim3(512), 0, stream,
                     features, W1, b2, b3, wsu, out);
}

// Round 6
// 172.942 us; speedup vs baseline: 1.0160x; 1.0160x over previous
//
#include <hip/hip_runtime.h>

// MiddleDecoder fused MLP, MFMA edition (32x32x16 bf16).
// Kernel T: weight transposes -> ws (bf16), batch output.
// Kernel S: S = b1 + feat@W1[3:], rel = pf@Wn + bn, out0.   (MFMA)
// Kernel M: h1 build in-reg -> swapped layer2 MFMA -> shfl half-swap -> layer3 MFMA.
// R4: 4pts/g buffered-build: 135us (MfmaUtil 18, VALU 42, conflicts 3.6M).
// R5: 2pts/g: 144us REGRESSION — af reuse halved (conflicts 7.2M), VGPR 80 =>
//     no pipelining; more waves didn't help => latency-bound, not TLP-bound.
// R6: 4pts/g + per-ks fused build+MFMA (VALU||MFMA overlap), b2/b3/W1 in LDS,
//     unroll4 + launch_bounds(512,2) for deep load pipelining.

#define NPTS 50000
#define MROWS (NPTS * 16)
#define OFF_FC3 ((size_t)MROWS * 3)
#define OFF_BATCH ((size_t)MROWS * 35)

typedef unsigned int uint_;
typedef unsigned short ushort_;
typedef __attribute__((ext_vector_type(8))) short bf16x8s;
typedef __attribute__((ext_vector_type(16))) float f32x16;

#define MFMA(a, b, c) __builtin_amdgcn_mfma_f32_32x32x16_bf16(a, b, c, 0, 0, 0)
#define CROW(r, h) (((r) & 3) + 8 * ((r) >> 2) + 4 * (h))

// ws layout (ushort offsets): W2T[128][256] @0 | W3T[32][128] @32768 |
// W1pT[256][128] @36864 | WnT[64][32] @69632 | S[50000][256] @71680 | rel f32 after.
#define WS_W2T 0
#define WS_W3T 32768
#define WS_W1PT 36864
#define WS_WNT 69632
#define WS_S 71680
#define WS_REL_BYTES 25743360

__device__ __forceinline__ float bl(uint_ u) { return __uint_as_float(u << 16); }
__device__ __forceinline__ float bh(uint_ u) { return __uint_as_float(u & 0xffff0000u); }
__device__ __forceinline__ ushort_ f2b(float f) {  // RNE f32->bf16
  uint_ u = __float_as_uint(f);
  u += 0x7fffu + ((u >> 16) & 1u);
  return (ushort_)(u >> 16);
}
__device__ __forceinline__ uint_ cvtpk(float lo, float hi) {
  uint_ r;
  asm("v_cvt_pk_bf16_f32 %0, %1, %2" : "=v"(r) : "v"(lo), "v"(hi));
  return r;
}
__device__ __forceinline__ float relu_(float x) { return fmaxf(x, 0.f); }

template<bool F32>
__device__ __forceinline__ float ldv(const void* p, int i) {
  if (F32) return ((const float*)p)[i];
  return bl((uint_)((const ushort_*)p)[i]);
}

struct F8 { float v[8]; };
template<bool F32>
__device__ __forceinline__ F8 ld8(const void* p, int idx) {  // idx multiple of 8
  F8 r;
  if (F32) {
    float4 a = *(const float4*)((const float*)p + idx);
    float4 b = *(const float4*)((const float*)p + idx + 4);
    r.v[0] = a.x; r.v[1] = a.y; r.v[2] = a.z; r.v[3] = a.w;
    r.v[4] = b.x; r.v[5] = b.y; r.v[6] = b.z; r.v[7] = b.w;
  } else {
    uint4 u = *(const uint4*)((const ushort_*)p + idx);
    r.v[0] = bl(u.x); r.v[1] = bh(u.x); r.v[2] = bl(u.y); r.v[3] = bh(u.y);
    r.v[4] = bl(u.z); r.v[5] = bh(u.z); r.v[6] = bl(u.w); r.v[7] = bh(u.w);
  }
  return r;
}
__device__ __forceinline__ F8 ld8lds(const float* p) {  // 32B-aligned LDS read
  F8 r;
  float4 a = *(const float4*)p;
  float4 b = *(const float4*)(p + 4);
  r.v[0] = a.x; r.v[1] = a.y; r.v[2] = a.z; r.v[3] = a.w;
  r.v[4] = b.x; r.v[5] = b.y; r.v[6] = b.z; r.v[7] = b.w;
  return r;
}
template<bool F32>
__device__ __forceinline__ void ld4f(const void* p, int idx, float* o) {  // idx mult of 4
  if (F32) {
    float4 v = *(const float4*)((const float*)p + idx);
    o[0] = v.x; o[1] = v.y; o[2] = v.z; o[3] = v.w;
  } else {
    uint2 v = *(const uint2*)((const ushort_*)p + idx);
    o[0] = bl(v.x); o[1] = bh(v.x); o[2] = bl(v.y); o[3] = bh(v.y);
  }
}

union FragU { uint_ u[4]; uint4 q; bf16x8s v; };
__device__ __forceinline__ bf16x8s pack8(const F8& f) {
  FragU o;
  #pragma unroll
  for (int j = 0; j < 4; ++j) o.u[j] = cvtpk(f.v[2 * j], f.v[2 * j + 1]);
  return o.v;
}

// true -> f32 inputs. bf16 N(0,1): all 32 u16 have plausible exponent; f32 ~58%.
__device__ __forceinline__ bool sniff_f32(const void* feats) {
  const ushort_* u = (const ushort_*)feats;
  int pass = 0;
  #pragma unroll 8
  for (int m = 0; m < 32; ++m) {
    int ex = (u[m] >> 7) & 0xff;
    pass += (ex >= 100 && ex <= 140) ? 1 : 0;
  }
  return pass < 28;
}

// ---------------- Kernel T: transposes + batch ----------------
__global__ void __launch_bounds__(256)
kT(const void* features, const void* batch, const void* W1, const void* Wn,
   const void* W2, const void* W3, ushort_* wsu, float* out) {
  bool f32 = sniff_f32(features);
  const uint_* bu = (const uint_*)batch;
  int nz = 0;
  #pragma unroll
  for (int m = 0; m < 16; ++m) nz += (bu[49999 - 2 * m] != 0u) ? 1 : 0;
  bool i64 = (nz == 0);

  const int total = 32768 + 32768 + 4096 + 2048 + 800000;
  for (int i = blockIdx.x * 256 + threadIdx.x; i < total; i += gridDim.x * 256) {
    if (i < 32768) {                       // W1pT[n*128+k] = W1[(3+k)*256+n]
      int n = i & 255, k = i >> 8;
      wsu[WS_W1PT + n * 128 + k] = f32 ? f2b(((const float*)W1)[(3 + k) * 256 + n])
                                       : ((const ushort_*)W1)[(3 + k) * 256 + n];
    } else if (i < 65536) {                // W2T[n*256+k] = W2[k*128+n]
      int i2 = i - 32768, n = i2 & 127, k = i2 >> 7;
      wsu[WS_W2T + n * 256 + k] = f32 ? f2b(((const float*)W2)[k * 128 + n])
                                      : ((const ushort_*)W2)[k * 128 + n];
    } else if (i < 69632) {                // W3T[n*128+k] = W3[k*32+n]
      int i3 = i - 65536, n = i3 & 31, k = i3 >> 5;
      wsu[WS_W3T + n * 128 + k] = f32 ? f2b(((const float*)W3)[k * 32 + n])
                                      : ((const ushort_*)W3)[k * 32 + n];
    } else if (i < 71680) {                // WnT[n*32+k] = Wn[k*48+n], rows>=48 zero
      int i4 = i - 69632, n = i4 >> 5, k = i4 & 31;
      ushort_ v = 0;
      if (n < 48) v = f32 ? f2b(((const float*)Wn)[k * 48 + n])
                          : ((const ushort_*)Wn)[k * 48 + n];
      wsu[WS_WNT + n * 32 + k] = v;
    } else {                               // batch output
      int g = i - 71680;
      int idx = g >> 4;
      int v = i64 ? (int)bu[2 * idx] : ((const int*)batch)[idx];
      out[OFF_BATCH + (size_t)g] = (float)v;
    }
  }
}

// ---------------- Kernel S: S, rel, out0 ----------------
template<bool F32>
__device__ void runS(const void* points, const void* features, const void* bn,
                     const void* b1, ushort_* wsu, float* out,
                     ushort_* w1pt, ushort_* feats) {
  const ushort_* W1pT_ws = wsu + WS_W1PT;
  const ushort_* WnT_ws = wsu + WS_WNT;
  ushort_* S_ws = wsu + WS_S;
  float* rel_ws = (float*)((char*)wsu + WS_REL_BYTES);
  const int tid = threadIdx.x;

  for (int c = tid; c < 4096; c += 256) {  // stage W1pT (256 rows x 256B) swizzled
    int n = c >> 4, s = c & 15;
    uint4 src = *(const uint4*)(W1pT_ws + c * 8);
    *(uint4*)((char*)w1pt + n * 256 + ((s * 16) ^ ((n & 7) << 4))) = src;
  }

  const int w = tid >> 6, lane = tid & 63, l31 = lane & 31, h = lane >> 5, h8 = h * 8;
  const int mt = w & 1, ctb = (w >> 1) * 4, ctr = w >> 1;

  for (int tile = blockIdx.x; tile < 782; tile += gridDim.x) {
    const int pbase = tile * 64;
    for (int c = tid; c < 2048; c += 256) {  // stage feat cols 32..160 bf16 swizzled
      int row = c >> 5, c4 = c & 31;
      int p = pbase + row;
      uint2 d = {0u, 0u};
      if (p < NPTS) {
        if (F32) {
          float4 v = *(const float4*)((const float*)features + p * 160 + 32 + c4 * 4);
          d.x = cvtpk(v.x, v.y); d.y = cvtpk(v.z, v.w);
        } else {
          d = *(const uint2*)((const ushort_*)features + p * 160 + 32 + c4 * 4);
        }
      }
      *(uint2*)((char*)feats + row * 256 + ((c4 * 8) ^ ((row & 7) << 4))) = d;
    }
    __syncthreads();

    // ---- S GEMM: A = feat rows, B = W1p ----
    bf16x8s af[8];
    #pragma unroll
    for (int ks = 0; ks < 8; ++ks) {
      int row = mt * 32 + l31;
      af[ks] = *(const bf16x8s*)((const char*)feats + row * 256 +
                                 (((ks * 16 + h8) * 2) ^ ((row & 7) << 4)));
    }
    #pragma unroll
    for (int ci = 0; ci < 4; ++ci) {
      int ct = ctb + ci;
      float b1v = ldv<F32>(b1, ct * 32 + l31);
      f32x16 acc;
      #pragma unroll
      for (int r = 0; r < 16; ++r) acc[r] = b1v;
      #pragma unroll
      for (int ks = 0; ks < 8; ++ks) {
        int n = ct * 32 + l31;
        bf16x8s bf = *(const bf16x8s*)((const char*)w1pt + n * 256 +
                                       (((ks * 16 + h8) * 2) ^ ((n & 7) << 4)));
        acc = MFMA(af[ks], bf, acc);
      }
      #pragma unroll
      for (int r = 0; r < 16; ++r) {
        int p = pbase + mt * 32 + CROW(r, h);
        if (p < NPTS) S_ws[p * 256 + ct * 32 + l31] = f2b(acc[r]);
      }
    }

    // ---- rel GEMM: A = pf (feat cols 0..32), B = Wn ----
    {
      int pm = pbase + mt * 32 + l31;
      pm = pm < NPTS ? pm : NPTS - 1;
      bf16x8s ar[2];
      #pragma unroll
      for (int ks = 0; ks < 2; ++ks) {
        F8 v = ld8<F32>(features, pm * 160 + ks * 16 + h8);
        ar[ks] = pack8(v);
      }
      f32x16 acc;
      #pragma unroll
      for (int r = 0; r < 16; ++r) acc[r] = 0.f;
      #pragma unroll
      for (int ks = 0; ks < 2; ++ks) {
        int n = ctr * 32 + l31;
        FragU bw;
        bw.q = *(const uint4*)(WnT_ws + n * 32 + ks * 16 + h8);
        acc = MFMA(ar[ks], bw.v, acc);
      }
      int j = ctr * 32 + l31;
      if (j < 48) {
        float bnv = ldv<F32>(bn, j);
        int c = j - (j / 3) * 3;
        #pragma unroll
        for (int r = 0; r < 16; ++r) {
          int p = pbase + mt * 32 + CROW(r, h);
          if (p < NPTS) {
            float rv = acc[r] + bnv;
            rel_ws[p * 48 + j] = rv;
            out[(size_t)p * 48 + j] = ldv<F32>(points, p * 3 + c) + 0.25f * rv;
          }
        }
      }
    }
    __syncthreads();
  }
}

__global__ void __launch_bounds__(256, 2)
kS(const void* points, const void* features, const void* bn, const void* b1,
   ushort_* wsu, float* out) {
  __shared__ ushort_ w1pt[32768];  // 64KB
  __shared__ ushort_ feats[8192];  // 16KB
  if (sniff_f32(features))
    runS<true>(points, features, bn, b1, wsu, out, w1pt, feats);
  else
    runS<false>(points, features, bn, b1, wsu, out, w1pt, feats);
}

// ---------------- Kernel M: h1 build + layer2 + layer3 ----------------
__device__ __forceinline__ bf16x8s build8(uint4 s, const F8& wx, const F8& wy,
                                          const F8& wz, float r0, float r1, float r2) {
  uint_ su[4] = {s.x, s.y, s.z, s.w};
  F8 f;
  #pragma unroll
  for (int j = 0; j < 8; ++j) {
    uint_ u = su[j >> 1];
    float sv = (j & 1) ? bh(u) : bl(u);
    f.v[j] = relu_(sv + r0 * wx.v[j] + r1 * wy.v[j] + r2 * wz.v[j]);
  }
  return pack8(f);
}

__device__ __forceinline__ bf16x8s assemble(const f32x16& a, int base, bool lo) {
  float e[8];
  #pragma unroll
  for (int j = 0; j < 8; ++j) e[j] = relu_(a[base + j]);
  uint_ A0 = cvtpk(e[0], e[1]), A1 = cvtpk(e[2], e[3]);
  uint_ B0 = cvtpk(e[4], e[5]), B1 = cvtpk(e[6], e[7]);
  uint_ sA0 = (uint_)__shfl_xor((int)A0, 32);
  uint_ sA1 = (uint_)__shfl_xor((int)A1, 32);
  uint_ sB0 = (uint_)__shfl_xor((int)B0, 32);
  uint_ sB1 = (uint_)__shfl_xor((int)B1, 32);
  FragU o;
  o.u[0] = lo ? A0 : sB0;
  o.u[1] = lo ? A1 : sB1;
  o.u[2] = lo ? sA0 : B0;
  o.u[3] = lo ? sA1 : B1;
  return o.v;
}

template<bool F32>
__device__ void runM(const void* W1, const void* b2, const void* b3,
                     const ushort_* wsu, float* out,
                     ushort_* w2t, ushort_* w3t, float* w1f, float* b2f, float* b3f) {
  const ushort_* S_ws = wsu + WS_S;
  const float* rel_ws = (const float*)((const char*)wsu + WS_REL_BYTES);
  const int tid = threadIdx.x;

  // stage W2T (128 rows x 512B: n=c>>5, s=c&31) + W3T (32 x 256B) + W1 rows 0-2 +
  // b2/b3 as f32
  for (int c = tid; c < 4608; c += 512) {
    if (c < 4096) {
      int n = c >> 5, s = c & 31;
      uint4 src = *(const uint4*)(wsu + WS_W2T + c * 8);
      *(uint4*)((char*)w2t + n * 512 + ((s * 16) ^ ((n & 7) << 4))) = src;
    } else {
      int c2 = c - 4096, n = c2 >> 4, s = c2 & 15;
      uint4 src = *(const uint4*)(wsu + WS_W3T + c2 * 8);
      *(uint4*)((char*)w3t + n * 256 + ((s * 16) ^ ((n & 7) << 4))) = src;
    }
  }
  for (int c = tid; c < 768; c += 512) w1f[c] = ldv<F32>(W1, c);
  if (tid < 128) b2f[tid] = ldv<F32>(b2, tid);
  if (tid < 32) b3f[tid] = ldv<F32>(b3, tid);
  __syncthreads();

  const int w = tid >> 6, lane = tid & 63, l31 = lane & 31, h = lane >> 5;
  const int h8 = h * 8, nb = lane & 15;
  const bool lo = lane < 32;
  const int slot = blockIdx.x * 8 + w;
  const int stride = gridDim.x * 8;

  for (int g = slot; g < 12500; g += stride) {
    const int p0 = g * 4;
    const int pA = p0 + (l31 >> 4), pB = pA + 2;
    const float rA0 = rel_ws[pA * 48 + nb * 3 + 0];
    const float rA1 = rel_ws[pA * 48 + nb * 3 + 1];
    const float rA2 = rel_ws[pA * 48 + nb * 3 + 2];
    const float rB0 = rel_ws[pB * 48 + nb * 3 + 0];
    const float rB1 = rel_ws[pB * 48 + nb * 3 + 1];
    const float rB2 = rel_ws[pB * 48 + nb * 3 + 2];

    f32x16 accA[4], accB[4];
    #pragma unroll
    for (int mt = 0; mt < 4; ++mt) {
      #pragma unroll
      for (int q = 0; q < 4; ++q) {
        float4 t = *(const float4*)(b2f + mt * 32 + q * 8 + 4 * h);
        accA[mt][4 * q + 0] = t.x; accA[mt][4 * q + 1] = t.y;
        accA[mt][4 * q + 2] = t.z; accA[mt][4 * q + 3] = t.w;
        accB[mt][4 * q + 0] = t.x; accB[mt][4 * q + 1] = t.y;
        accB[mt][4 * q + 2] = t.z; accB[mt][4 * q + 3] = t.w;
      }
    }

    // per-ks: build hA,hB (VALU) then 4x(af -> 2 MFMA): pipes overlap, af 2x reuse
    #pragma unroll 4
    for (int ks = 0; ks < 16; ++ks) {
      const int koff = ks * 16 + h8;
      uint4 sa = *(const uint4*)(S_ws + pA * 256 + koff);
      uint4 sb = *(const uint4*)(S_ws + pB * 256 + koff);
      F8 wx = ld8lds(w1f + koff);
      F8 wy = ld8lds(w1f + 256 + koff);
      F8 wz = ld8lds(w1f + 512 + koff);
      bf16x8s hA = build8(sa, wx, wy, wz, rA0, rA1, rA2);
      bf16x8s hB = build8(sb, wx, wy, wz, rB0, rB1, rB2);
      const int kb = koff * 2;
      #pragma unroll
      for (int mt = 0; mt < 4; ++mt) {
        int n = mt * 32 + l31;
        bf16x8s af = *(const bf16x8s*)((const char*)w2t + n * 512 +
                                       (kb ^ ((n & 7) << 4)));
        accA[mt] = MFMA(af, hA, accA[mt]);
        accB[mt] = MFMA(af, hB, accB[mt]);
      }
    }

    // layer3: A = W3T (LDS), B = half-swapped relu(h2) from acc regs
    f32x16 o3A, o3B;
    #pragma unroll
    for (int q = 0; q < 4; ++q) {
      float4 t = *(const float4*)(b3f + q * 8 + 4 * h);
      o3A[4 * q + 0] = t.x; o3A[4 * q + 1] = t.y;
      o3A[4 * q + 2] = t.z; o3A[4 * q + 3] = t.w;
      o3B[4 * q + 0] = t.x; o3B[4 * q + 1] = t.y;
      o3B[4 * q + 2] = t.z; o3B[4 * q + 3] = t.w;
    }
    #pragma unroll
    for (int ks3 = 0; ks3 < 8; ++ks3) {
      int kb = (ks3 * 16 + h8) * 2;
      bf16x8s a3 = *(const bf16x8s*)((const char*)w3t + l31 * 256 +
                                     (kb ^ ((l31 & 7) << 4)));
      const int mt = ks3 >> 1, base = (ks3 & 1) * 8;
      bf16x8s B3A = assemble(accA[mt], base, lo);
      bf16x8s B3B = assemble(accB[mt], base, lo);
      o3A = MFMA(a3, B3A, o3A);
      o3B = MFMA(a3, B3B, o3B);
    }

    const size_t rowA = (size_t)p0 * 16 + l31;
    #pragma unroll
    for (int q = 0; q < 4; ++q) {
      float4 vA = {relu_(o3A[4 * q]), relu_(o3A[4 * q + 1]),
                   relu_(o3A[4 * q + 2]), relu_(o3A[4 * q + 3])};
      float4 vB = {relu_(o3B[4 * q]), relu_(o3B[4 * q + 1]),
                   relu_(o3B[4 * q + 2]), relu_(o3B[4 * q + 3])};
      *(float4*)(out + OFF_FC3 + rowA * 32 + q * 8 + 4 * h) = vA;
      *(float4*)(out + OFF_FC3 + (rowA + 32) * 32 + q * 8 + 4 * h) = vB;
    }
  }
}

__global__ void __launch_bounds__(512, 2)
kM(const void* features, const void* W1, const void* b2, const void* b3,
   const ushort_* wsu, float* out) {
  __shared__ ushort_ w2t[32768];  // 64KB swizzled
  __shared__ ushort_ w3t[4096];   // 8KB swizzled
  __shared__ float w1f[768];      // 3KB W1 rows 0-2
  __shared__ float b2f[128];
  __shared__ float b3f[32];
  if (sniff_f32(features))
    runM<true>(W1, b2, b3, wsu, out, w2t, w3t, w1f, b2f, b3f);
  else
    runM<false>(W1, b2, b3, wsu, out, w2t, w3t, w1f, b2f, b3f);
}

extern "C" void kernel_launch(void* const* d_in, const int* in_sizes, int n_in,
                              void* d_out, int out_size, void* d_ws, size_t ws_size,
                              hipStream_t stream) {
  const void* points   = d_in[0];
  const void* features = d_in[1];
  const void* batch    = d_in[2];
  const void* Wn = d_in[3];  const void* bn = d_in[4];
  const void* W1 = d_in[5];  const void* b1 = d_in[6];
  const void* W2 = d_in[7];  const void* b2 = d_in[8];
  const void* W3 = d_in[9];  const void* b3 = d_in[10];
  float* out = (float*)d_out;
  ushort_* wsu = (ushort_*)d_ws;

  hipLaunchKernelGGL(kT, dim3(512), dim3(256), 0, stream,
                     features, batch, W1, Wn, W2, W3, wsu, out);
  hipLaunchKernelGGL(kS, dim3(782), dim3(256), 0, stream,
                     points, features, bn, b1, wsu, out);
  hipLaunchKernelGGL(kM, dim3(512), dim3(512), 0, stream,
                     features, W1, b2, b3, wsu, out);
}

// Round 7
// 151.084 us; speedup vs baseline: 1.1630x; 1.1447x over previous
//
#include <hip/hip_runtime.h>

// MiddleDecoder fused MLP, MFMA edition (32x32x16 bf16).
// Kernel T: weight transposes -> ws (bf16), batch output.
// Kernel S: S = b1 + feat@W1[3:], rel = pf@Wn + bn, out0.   (MFMA)
// Kernel M: rel-GEMM with S folded in as K-slots -> layer2 MFMA -> layer3 MFMA.
// R4-R6: h1 built on VALU (build8): all ~135-146us, VALUBusy~42 MfmaUtil~17.
// R7: h1pre = MFMA(X,Y) where X[n1][k]: k0..2=W1r3, k3=S[pt0][n1], k4=S[pt1][n1];
//     Y[m][k]: k0..2=rel[m], k3=(m<16), k4=(m>=16). Zero VALU h1 build; assemble
//     (verified in layer3) repacks C->B-frag with relu.

#define NPTS 50000
#define MROWS (NPTS * 16)
#define OFF_FC3 ((size_t)MROWS * 3)
#define OFF_BATCH ((size_t)MROWS * 35)

typedef unsigned int uint_;
typedef unsigned short ushort_;
typedef __attribute__((ext_vector_type(8))) short bf16x8s;
typedef __attribute__((ext_vector_type(16))) float f32x16;

#define MFMA(a, b, c) __builtin_amdgcn_mfma_f32_32x32x16_bf16(a, b, c, 0, 0, 0)
#define CROW(r, h) (((r) & 3) + 8 * ((r) >> 2) + 4 * (h))

// ws layout (ushort offsets): W2T[128][256] @0 | W3T[32][128] @32768 |
// W1pT[256][128] @36864 | WnT[64][32] @69632 | S[50000][256] @71680 | rel f32 after.
#define WS_W2T 0
#define WS_W3T 32768
#define WS_W1PT 36864
#define WS_WNT 69632
#define WS_S 71680
#define WS_REL_BYTES 25743360

__device__ __forceinline__ float bl(uint_ u) { return __uint_as_float(u << 16); }
__device__ __forceinline__ float bh(uint_ u) { return __uint_as_float(u & 0xffff0000u); }
__device__ __forceinline__ ushort_ f2b(float f) {  // RNE f32->bf16
  uint_ u = __float_as_uint(f);
  u += 0x7fffu + ((u >> 16) & 1u);
  return (ushort_)(u >> 16);
}
__device__ __forceinline__ uint_ cvtpk(float lo, float hi) {
  uint_ r;
  asm("v_cvt_pk_bf16_f32 %0, %1, %2" : "=v"(r) : "v"(lo), "v"(hi));
  return r;
}
__device__ __forceinline__ float relu_(float x) { return fmaxf(x, 0.f); }

template<bool F32>
__device__ __forceinline__ float ldv(const void* p, int i) {
  if (F32) return ((const float*)p)[i];
  return bl((uint_)((const ushort_*)p)[i]);
}

struct F8 { float v[8]; };
template<bool F32>
__device__ __forceinline__ F8 ld8(const void* p, int idx) {  // idx multiple of 8
  F8 r;
  if (F32) {
    float4 a = *(const float4*)((const float*)p + idx);
    float4 b = *(const float4*)((const float*)p + idx + 4);
    r.v[0] = a.x; r.v[1] = a.y; r.v[2] = a.z; r.v[3] = a.w;
    r.v[4] = b.x; r.v[5] = b.y; r.v[6] = b.z; r.v[7] = b.w;
  } else {
    uint4 u = *(const uint4*)((const ushort_*)p + idx);
    r.v[0] = bl(u.x); r.v[1] = bh(u.x); r.v[2] = bl(u.y); r.v[3] = bh(u.y);
    r.v[4] = bl(u.z); r.v[5] = bh(u.z); r.v[6] = bl(u.w); r.v[7] = bh(u.w);
  }
  return r;
}

union FragU { uint_ u[4]; uint4 q; bf16x8s v; };
__device__ __forceinline__ bf16x8s pack8(const F8& f) {
  FragU o;
  #pragma unroll
  for (int j = 0; j < 4; ++j) o.u[j] = cvtpk(f.v[2 * j], f.v[2 * j + 1]);
  return o.v;
}

// true -> f32 inputs. bf16 N(0,1): all 32 u16 have plausible exponent; f32 ~58%.
__device__ __forceinline__ bool sniff_f32(const void* feats) {
  const ushort_* u = (const ushort_*)feats;
  int pass = 0;
  #pragma unroll 8
  for (int m = 0; m < 32; ++m) {
    int ex = (u[m] >> 7) & 0xff;
    pass += (ex >= 100 && ex <= 140) ? 1 : 0;
  }
  return pass < 28;
}

// ---------------- Kernel T: transposes + batch ----------------
__global__ void __launch_bounds__(256)
kT(const void* features, const void* batch, const void* W1, const void* Wn,
   const void* W2, const void* W3, ushort_* wsu, float* out) {
  bool f32 = sniff_f32(features);
  const uint_* bu = (const uint_*)batch;
  int nz = 0;
  #pragma unroll
  for (int m = 0; m < 16; ++m) nz += (bu[49999 - 2 * m] != 0u) ? 1 : 0;
  bool i64 = (nz == 0);

  const int total = 32768 + 32768 + 4096 + 2048 + 800000;
  for (int i = blockIdx.x * 256 + threadIdx.x; i < total; i += gridDim.x * 256) {
    if (i < 32768) {                       // W1pT[n*128+k] = W1[(3+k)*256+n]
      int n = i & 255, k = i >> 8;
      wsu[WS_W1PT + n * 128 + k] = f32 ? f2b(((const float*)W1)[(3 + k) * 256 + n])
                                       : ((const ushort_*)W1)[(3 + k) * 256 + n];
    } else if (i < 65536) {                // W2T[n*256+k] = W2[k*128+n]
      int i2 = i - 32768, n = i2 & 127, k = i2 >> 7;
      wsu[WS_W2T + n * 256 + k] = f32 ? f2b(((const float*)W2)[k * 128 + n])
                                      : ((const ushort_*)W2)[k * 128 + n];
    } else if (i < 69632) {                // W3T[n*128+k] = W3[k*32+n]
      int i3 = i - 65536, n = i3 & 31, k = i3 >> 5;
      wsu[WS_W3T + n * 128 + k] = f32 ? f2b(((const float*)W3)[k * 32 + n])
                                      : ((const ushort_*)W3)[k * 32 + n];
    } else if (i < 71680) {                // WnT[n*32+k] = Wn[k*48+n], rows>=48 zero
      int i4 = i - 69632, n = i4 >> 5, k = i4 & 31;
      ushort_ v = 0;
      if (n < 48) v = f32 ? f2b(((const float*)Wn)[k * 48 + n])
                          : ((const ushort_*)Wn)[k * 48 + n];
      wsu[WS_WNT + n * 32 + k] = v;
    } else {                               // batch output
      int g = i - 71680;
      int idx = g >> 4;
      int v = i64 ? (int)bu[2 * idx] : ((const int*)batch)[idx];
      out[OFF_BATCH + (size_t)g] = (float)v;
    }
  }
}

// ---------------- Kernel S: S, rel, out0 ----------------
template<bool F32>
__device__ void runS(const void* points, const void* features, const void* bn,
                     const void* b1, ushort_* wsu, float* out,
                     ushort_* w1pt, ushort_* feats) {
  const ushort_* W1pT_ws = wsu + WS_W1PT;
  const ushort_* WnT_ws = wsu + WS_WNT;
  ushort_* S_ws = wsu + WS_S;
  float* rel_ws = (float*)((char*)wsu + WS_REL_BYTES);
  const int tid = threadIdx.x;

  for (int c = tid; c < 4096; c += 256) {  // stage W1pT (256 rows x 256B) swizzled
    int n = c >> 4, s = c & 15;
    uint4 src = *(const uint4*)(W1pT_ws + c * 8);
    *(uint4*)((char*)w1pt + n * 256 + ((s * 16) ^ ((n & 7) << 4))) = src;
  }

  const int w = tid >> 6, lane = tid & 63, l31 = lane & 31, h = lane >> 5, h8 = h * 8;
  const int mt = w & 1, ctb = (w >> 1) * 4, ctr = w >> 1;

  for (int tile = blockIdx.x; tile < 782; tile += gridDim.x) {
    const int pbase = tile * 64;
    for (int c = tid; c < 2048; c += 256) {  // stage feat cols 32..160 bf16 swizzled
      int row = c >> 5, c4 = c & 31;
      int p = pbase + row;
      uint2 d = {0u, 0u};
      if (p < NPTS) {
        if (F32) {
          float4 v = *(const float4*)((const float*)features + p * 160 + 32 + c4 * 4);
          d.x = cvtpk(v.x, v.y); d.y = cvtpk(v.z, v.w);
        } else {
          d = *(const uint2*)((const ushort_*)features + p * 160 + 32 + c4 * 4);
        }
      }
      *(uint2*)((char*)feats + row * 256 + ((c4 * 8) ^ ((row & 7) << 4))) = d;
    }
    __syncthreads();

    // ---- S GEMM: A = feat rows, B = W1p ----
    bf16x8s af[8];
    #pragma unroll
    for (int ks = 0; ks < 8; ++ks) {
      int row = mt * 32 + l31;
      af[ks] = *(const bf16x8s*)((const char*)feats + row * 256 +
                                 (((ks * 16 + h8) * 2) ^ ((row & 7) << 4)));
    }
    #pragma unroll
    for (int ci = 0; ci < 4; ++ci) {
      int ct = ctb + ci;
      float b1v = ldv<F32>(b1, ct * 32 + l31);
      f32x16 acc;
      #pragma unroll
      for (int r = 0; r < 16; ++r) acc[r] = b1v;
      #pragma unroll
      for (int ks = 0; ks < 8; ++ks) {
        int n = ct * 32 + l31;
        bf16x8s bf = *(const bf16x8s*)((const char*)w1pt + n * 256 +
                                       (((ks * 16 + h8) * 2) ^ ((n & 7) << 4)));
        acc = MFMA(af[ks], bf, acc);
      }
      #pragma unroll
      for (int r = 0; r < 16; ++r) {
        int p = pbase + mt * 32 + CROW(r, h);
        if (p < NPTS) S_ws[p * 256 + ct * 32 + l31] = f2b(acc[r]);
      }
    }

    // ---- rel GEMM: A = pf (feat cols 0..32), B = Wn ----
    {
      int pm = pbase + mt * 32 + l31;
      pm = pm < NPTS ? pm : NPTS - 1;
      bf16x8s ar[2];
      #pragma unroll
      for (int ks = 0; ks < 2; ++ks) {
        F8 v = ld8<F32>(features, pm * 160 + ks * 16 + h8);
        ar[ks] = pack8(v);
      }
      f32x16 acc;
      #pragma unroll
      for (int r = 0; r < 16; ++r) acc[r] = 0.f;
      #pragma unroll
      for (int ks = 0; ks < 2; ++ks) {
        int n = ctr * 32 + l31;
        FragU bw;
        bw.q = *(const uint4*)(WnT_ws + n * 32 + ks * 16 + h8);
        acc = MFMA(ar[ks], bw.v, acc);
      }
      int j = ctr * 32 + l31;
      if (j < 48) {
        float bnv = ldv<F32>(bn, j);
        int c = j - (j / 3) * 3;
        #pragma unroll
        for (int r = 0; r < 16; ++r) {
          int p = pbase + mt * 32 + CROW(r, h);
          if (p < NPTS) {
            float rv = acc[r] + bnv;
            rel_ws[p * 48 + j] = rv;
            out[(size_t)p * 48 + j] = ldv<F32>(points, p * 3 + c) + 0.25f * rv;
          }
        }
      }
    }
    __syncthreads();
  }
}

__global__ void __launch_bounds__(256, 2)
kS(const void* points, const void* features, const void* bn, const void* b1,
   ushort_* wsu, float* out) {
  __shared__ ushort_ w1pt[32768];  // 64KB
  __shared__ ushort_ feats[8192];  // 16KB
  if (sniff_f32(features))
    runS<true>(points, features, bn, b1, wsu, out, w1pt, feats);
  else
    runS<false>(points, features, bn, b1, wsu, out, w1pt, feats);
}

// ---------------- Kernel M ----------------
// assemble: C-layout acc (lane=m, reg->channel via CROW) -> B-frag (lane=m,
// regs = 8 consecutive channels), with relu. Verified by layer3 in R4.
__device__ __forceinline__ bf16x8s assemble(const f32x16& a, int base, bool lo) {
  float e[8];
  #pragma unroll
  for (int j = 0; j < 8; ++j) e[j] = relu_(a[base + j]);
  uint_ A0 = cvtpk(e[0], e[1]), A1 = cvtpk(e[2], e[3]);
  uint_ B0 = cvtpk(e[4], e[5]), B1 = cvtpk(e[6], e[7]);
  uint_ sA0 = (uint_)__shfl_xor((int)A0, 32);
  uint_ sA1 = (uint_)__shfl_xor((int)A1, 32);
  uint_ sB0 = (uint_)__shfl_xor((int)B0, 32);
  uint_ sB1 = (uint_)__shfl_xor((int)B1, 32);
  FragU o;
  o.u[0] = lo ? A0 : sB0;
  o.u[1] = lo ? A1 : sB1;
  o.u[2] = lo ? sA0 : B0;
  o.u[3] = lo ? sA1 : B1;
  return o.v;
}

template<bool F32>
__device__ void runM(const void* W1, const void* b2, const void* b3,
                     const ushort_* wsu, float* out,
                     ushort_* w2t, ushort_* w3t, uint_* w1x, float* b2f, float* b3f) {
  const ushort_* S_ws = wsu + WS_S;
  const float* rel_ws = (const float*)((const char*)wsu + WS_REL_BYTES);
  const int tid = threadIdx.x;

  // stage W2T (128 rows x 512B: n=c>>5, s=c&31) + W3T (32 x 256B) swizzled,
  // w1x[n1] = {(W10,W11),(W12,0)} packed bf16, b2/b3 f32
  for (int c = tid; c < 4608; c += 512) {
    if (c < 4096) {
      int n = c >> 5, s = c & 31;
      uint4 src = *(const uint4*)(wsu + WS_W2T + c * 8);
      *(uint4*)((char*)w2t + n * 512 + ((s * 16) ^ ((n & 7) << 4))) = src;
    } else {
      int c2 = c - 4096, n = c2 >> 4, s = c2 & 15;
      uint4 src = *(const uint4*)(wsu + WS_W3T + c2 * 8);
      *(uint4*)((char*)w3t + n * 256 + ((s * 16) ^ ((n & 7) << 4))) = src;
    }
  }
  if (tid < 256) {
    float w0 = ldv<F32>(W1, 0 * 256 + tid);
    float w1v = ldv<F32>(W1, 1 * 256 + tid);
    float w2v = ldv<F32>(W1, 2 * 256 + tid);
    w1x[tid * 2 + 0] = cvtpk(w0, w1v);
    w1x[tid * 2 + 1] = cvtpk(w2v, 0.f);
  }
  if (tid < 128) b2f[tid] = ldv<F32>(b2, tid);
  if (tid < 32) b3f[tid] = ldv<F32>(b3, tid);
  __syncthreads();

  const int w = tid >> 6, lane = tid & 63, l31 = lane & 31, h = lane >> 5;
  const bool lo = lane < 32;
  const int slot = blockIdx.x * 8 + w;
  const int stride = gridDim.x * 8;

  f32x16 zero16;
  #pragma unroll
  for (int r = 0; r < 16; ++r) zero16[r] = 0.f;

  for (int g = slot; g < 12500; g += stride) {
    const int p0 = g * 4;

    // Y-frags per tile t (points p0+2t, p0+2t+1): lane&31 = row m; k-slots:
    // k0..2 = rel[row], k3 = (m<16), k4 = (m>=16). h-half lanes (k8..15) zero.
    bf16x8s yf[2];
    #pragma unroll
    for (int t = 0; t < 2; ++t) {
      int p = p0 + 2 * t + (l31 >> 4);
      const float* rp = rel_ws + p * 48 + (l31 & 15) * 3;
      float r0 = rp[0], r1 = rp[1], r2 = rp[2];
      float selA = (l31 >> 4) ? 0.f : 1.f;
      float selB = 1.f - selA;
      FragU y;
      y.u[0] = h ? 0u : cvtpk(r0, r1);
      y.u[1] = h ? 0u : cvtpk(r2, selA);
      y.u[2] = h ? 0u : cvtpk(selB, 0.f);
      y.u[3] = 0u;
      yf[t] = y.v;
    }

    f32x16 accA[4], accB[4];
    #pragma unroll
    for (int mt = 0; mt < 4; ++mt) {
      #pragma unroll
      for (int q = 0; q < 4; ++q) {
        float4 t4 = *(const float4*)(b2f + mt * 32 + q * 8 + 4 * h);
        accA[mt][4 * q + 0] = t4.x; accA[mt][4 * q + 1] = t4.y;
        accA[mt][4 * q + 2] = t4.z; accA[mt][4 * q + 3] = t4.w;
        accB[mt][4 * q + 0] = t4.x; accB[mt][4 * q + 1] = t4.y;
        accB[mt][4 * q + 2] = t4.z; accB[mt][4 * q + 3] = t4.w;
      }
    }

    #pragma unroll 1
    for (int grp = 0; grp < 8; ++grp) {
      const int c0 = grp * 32;
      // X-frags: lane&31 = n1 = c0+l31; k0..2 = W1r3[n1], k3 = S[pt0][n1],
      // k4 = S[pt1][n1]. h-half lanes zero.
      uint2 wp = *(const uint2*)(w1x + (c0 + l31) * 2);
      f32x16 acc1[2];
      #pragma unroll
      for (int t = 0; t < 2; ++t) {
        int pa = p0 + 2 * t;
        uint_ s0 = (uint_)S_ws[pa * 256 + c0 + l31];
        uint_ s1 = (uint_)S_ws[(pa + 1) * 256 + c0 + l31];
        FragU x;
        x.u[0] = h ? 0u : wp.x;
        x.u[1] = h ? 0u : ((wp.y & 0xffffu) | (s0 << 16));
        x.u[2] = h ? 0u : s1;
        x.u[3] = 0u;
        acc1[t] = MFMA(x.v, yf[t], zero16);
      }
      // layer2: two 16-k slices from this 32-channel group
      #pragma unroll
      for (int b = 0; b < 2; ++b) {
        bf16x8s hA = assemble(acc1[0], b * 8, lo);
        bf16x8s hB = assemble(acc1[1], b * 8, lo);
        const int kb = (c0 + b * 16 + h * 8) * 2;
        #pragma unroll
        for (int mt = 0; mt < 4; ++mt) {
          int n = mt * 32 + l31;
          bf16x8s af = *(const bf16x8s*)((const char*)w2t + n * 512 +
                                         (kb ^ ((n & 7) << 4)));
          accA[mt] = MFMA(af, hA, accA[mt]);
          accB[mt] = MFMA(af, hB, accB[mt]);
        }
      }
    }

    // layer3: A = W3T (LDS), B = half-swapped relu(h2) from acc regs
    f32x16 o3A, o3B;
    #pragma unroll
    for (int q = 0; q < 4; ++q) {
      float4 t4 = *(const float4*)(b3f + q * 8 + 4 * h);
      o3A[4 * q + 0] = t4.x; o3A[4 * q + 1] = t4.y;
      o3A[4 * q + 2] = t4.z; o3A[4 * q + 3] = t4.w;
      o3B[4 * q + 0] = t4.x; o3B[4 * q + 1] = t4.y;
      o3B[4 * q + 2] = t4.z; o3B[4 * q + 3] = t4.w;
    }
    #pragma unroll
    for (int ks3 = 0; ks3 < 8; ++ks3) {
      int kb = (ks3 * 16 + h * 8) * 2;
      bf16x8s a3 = *(const bf16x8s*)((const char*)w3t + l31 * 256 +
                                     (kb ^ ((l31 & 7) << 4)));
      const int mt = ks3 >> 1, base = (ks3 & 1) * 8;
      bf16x8s B3A = assemble(accA[mt], base, lo);
      bf16x8s B3B = assemble(accB[mt], base, lo);
      o3A = MFMA(a3, B3A, o3A);
      o3B = MFMA(a3, B3B, o3B);
    }

    const size_t rowA = (size_t)p0 * 16 + l31;
    #pragma unroll
    for (int q = 0; q < 4; ++q) {
      float4 vA = {relu_(o3A[4 * q]), relu_(o3A[4 * q + 1]),
                   relu_(o3A[4 * q + 2]), relu_(o3A[4 * q + 3])};
      float4 vB = {relu_(o3B[4 * q]), relu_(o3B[4 * q + 1]),
                   relu_(o3B[4 * q + 2]), relu_(o3B[4 * q + 3])};
      *(float4*)(out + OFF_FC3 + rowA * 32 + q * 8 + 4 * h) = vA;
      *(float4*)(out + OFF_FC3 + (rowA + 32) * 32 + q * 8 + 4 * h) = vB;
    }
  }
}

__global__ void __launch_bounds__(512, 2)
kM(const void* features, const void* W1, const void* b2, const void* b3,
   const ushort_* wsu, float* out) {
  __shared__ ushort_ w2t[32768];  // 64KB swizzled
  __shared__ ushort_ w3t[4096];   // 8KB swizzled
  __shared__ uint_ w1x[512];      // 2KB: per n1 packed (W10,W11),(W12,0)
  __shared__ float b2f[128];
  __shared__ float b3f[32];
  if (sniff_f32(features))
    runM<true>(W1, b2, b3, wsu, out, w2t, w3t, w1x, b2f, b3f);
  else
    runM<false>(W1, b2, b3, wsu, out, w2t, w3t, w1x, b2f, b3f);
}

extern "C" void kernel_launch(void* const* d_in, const int* in_sizes, int n_in,
                              void* d_out, int out_size, void* d_ws, size_t ws_size,
                              hipStream_t stream) {
  const void* points   = d_in[0];
  const void* features = d_in[1];
  const void* batch    = d_in[2];
  const void* Wn = d_in[3];  const void* bn = d_in[4];
  const void* W1 = d_in[5];  const void* b1 = d_in[6];
  const void* W2 = d_in[7];  const void* b2 = d_in[8];
  const void* W3 = d_in[9];  const void* b3 = d_in[10];
  float* out = (float*)d_out;
  ushort_* wsu = (ushort_*)d_ws;

  hipLaunchKernelGGL(kT, dim3(512), dim3(256), 0, stream,
                     features, batch, W1, Wn, W2, W3, wsu, out);
  hipLaunchKernelGGL(kS, dim3(782), dim3(256), 0, stream,
                     points, features, bn, b1, wsu, out);
  hipLaunchKernelGGL(kM, dim3(512), dim3(512), 0, stream,
                     features, W1, b2, b3, wsu, out);
}

// Round 8
// 133.704 us; speedup vs baseline: 1.3141x; 1.1300x over previous
//
#include <hip/hip_runtime.h>

// MiddleDecoder fused MLP, MFMA edition (32x32x16 bf16).
// Kernel T: weight transposes -> ws (bf16), batch output.
// Kernel S: S = b1 + feat@W1[3:], rel = pf@Wn + bn, out0.   (MFMA)
// Kernel M: rel-GEMM with S folded in as K-slots -> layer2 MFMA -> layer3 MFMA.
// R7: h1 via MFMA K-slots: kM 146->117us (MfmaUtil 23, VALU 32). Still ~45% stall:
//     32 scalar S loads/g (HBM-latency) + ~320 acc-init movs/g.
// R8: (1) S4 quad-interleaved layout -> 8 coalesced uint2 loads/g;
//     (2) zero16-C first MFMA + biases folded into assemble/store (no acc init);
//     (3) grp loop fully unrolled for load pipelining.

#define NPTS 50000
#define MROWS (NPTS * 16)
#define OFF_FC3 ((size_t)MROWS * 3)
#define OFF_BATCH ((size_t)MROWS * 35)

typedef unsigned int uint_;
typedef unsigned short ushort_;
typedef __attribute__((ext_vector_type(8))) short bf16x8s;
typedef __attribute__((ext_vector_type(16))) float f32x16;

#define MFMA(a, b, c) __builtin_amdgcn_mfma_f32_32x32x16_bf16(a, b, c, 0, 0, 0)
#define CROW(r, h) (((r) & 3) + 8 * ((r) >> 2) + 4 * (h))

// ws layout (ushort offsets): W2T[128][256] @0 | W3T[32][128] @32768 |
// W1pT[256][128] @36864 | WnT[64][32] @69632 | S4[12500][256][4] @71680 | rel f32.
#define WS_W2T 0
#define WS_W3T 32768
#define WS_W1PT 36864
#define WS_WNT 69632
#define WS_S 71680
#define WS_REL_BYTES 25743360

__device__ __forceinline__ float bl(uint_ u) { return __uint_as_float(u << 16); }
__device__ __forceinline__ float bh(uint_ u) { return __uint_as_float(u & 0xffff0000u); }
__device__ __forceinline__ ushort_ f2b(float f) {  // RNE f32->bf16
  uint_ u = __float_as_uint(f);
  u += 0x7fffu + ((u >> 16) & 1u);
  return (ushort_)(u >> 16);
}
__device__ __forceinline__ uint_ cvtpk(float lo, float hi) {
  uint_ r;
  asm("v_cvt_pk_bf16_f32 %0, %1, %2" : "=v"(r) : "v"(lo), "v"(hi));
  return r;
}
__device__ __forceinline__ float relu_(float x) { return fmaxf(x, 0.f); }

template<bool F32>
__device__ __forceinline__ float ldv(const void* p, int i) {
  if (F32) return ((const float*)p)[i];
  return bl((uint_)((const ushort_*)p)[i]);
}

struct F8 { float v[8]; };
template<bool F32>
__device__ __forceinline__ F8 ld8(const void* p, int idx) {  // idx multiple of 8
  F8 r;
  if (F32) {
    float4 a = *(const float4*)((const float*)p + idx);
    float4 b = *(const float4*)((const float*)p + idx + 4);
    r.v[0] = a.x; r.v[1] = a.y; r.v[2] = a.z; r.v[3] = a.w;
    r.v[4] = b.x; r.v[5] = b.y; r.v[6] = b.z; r.v[7] = b.w;
  } else {
    uint4 u = *(const uint4*)((const ushort_*)p + idx);
    r.v[0] = bl(u.x); r.v[1] = bh(u.x); r.v[2] = bl(u.y); r.v[3] = bh(u.y);
    r.v[4] = bl(u.z); r.v[5] = bh(u.z); r.v[6] = bl(u.w); r.v[7] = bh(u.w);
  }
  return r;
}

union FragU { uint_ u[4]; uint4 q; bf16x8s v; };
__device__ __forceinline__ bf16x8s pack8(const F8& f) {
  FragU o;
  #pragma unroll
  for (int j = 0; j < 4; ++j) o.u[j] = cvtpk(f.v[2 * j], f.v[2 * j + 1]);
  return o.v;
}

// true -> f32 inputs. bf16 N(0,1): all 32 u16 have plausible exponent; f32 ~58%.
__device__ __forceinline__ bool sniff_f32(const void* feats) {
  const ushort_* u = (const ushort_*)feats;
  int pass = 0;
  #pragma unroll 8
  for (int m = 0; m < 32; ++m) {
    int ex = (u[m] >> 7) & 0xff;
    pass += (ex >= 100 && ex <= 140) ? 1 : 0;
  }
  return pass < 28;
}

// ---------------- Kernel T: transposes + batch ----------------
__global__ void __launch_bounds__(256)
kT(const void* features, const void* batch, const void* W1, const void* Wn,
   const void* W2, const void* W3, ushort_* wsu, float* out) {
  bool f32 = sniff_f32(features);
  const uint_* bu = (const uint_*)batch;
  int nz = 0;
  #pragma unroll
  for (int m = 0; m < 16; ++m) nz += (bu[49999 - 2 * m] != 0u) ? 1 : 0;
  bool i64 = (nz == 0);

  const int total = 32768 + 32768 + 4096 + 2048 + 800000;
  for (int i = blockIdx.x * 256 + threadIdx.x; i < total; i += gridDim.x * 256) {
    if (i < 32768) {                       // W1pT[n*128+k] = W1[(3+k)*256+n]
      int n = i & 255, k = i >> 8;
      wsu[WS_W1PT + n * 128 + k] = f32 ? f2b(((const float*)W1)[(3 + k) * 256 + n])
                                       : ((const ushort_*)W1)[(3 + k) * 256 + n];
    } else if (i < 65536) {                // W2T[n*256+k] = W2[k*128+n]
      int i2 = i - 32768, n = i2 & 127, k = i2 >> 7;
      wsu[WS_W2T + n * 256 + k] = f32 ? f2b(((const float*)W2)[k * 128 + n])
                                      : ((const ushort_*)W2)[k * 128 + n];
    } else if (i < 69632) {                // W3T[n*128+k] = W3[k*32+n]
      int i3 = i - 65536, n = i3 & 31, k = i3 >> 5;
      wsu[WS_W3T + n * 128 + k] = f32 ? f2b(((const float*)W3)[k * 32 + n])
                                      : ((const ushort_*)W3)[k * 32 + n];
    } else if (i < 71680) {                // WnT[n*32+k] = Wn[k*48+n], rows>=48 zero
      int i4 = i - 69632, n = i4 >> 5, k = i4 & 31;
      ushort_ v = 0;
      if (n < 48) v = f32 ? f2b(((const float*)Wn)[k * 48 + n])
                          : ((const ushort_*)Wn)[k * 48 + n];
      wsu[WS_WNT + n * 32 + k] = v;
    } else {                               // batch output
      int g = i - 71680;
      int idx = g >> 4;
      int v = i64 ? (int)bu[2 * idx] : ((const int*)batch)[idx];
      out[OFF_BATCH + (size_t)g] = (float)v;
    }
  }
}

// ---------------- Kernel S: S, rel, out0 ----------------
template<bool F32>
__device__ void runS(const void* points, const void* features, const void* bn,
                     const void* b1, ushort_* wsu, float* out,
                     ushort_* w1pt, ushort_* feats) {
  const ushort_* W1pT_ws = wsu + WS_W1PT;
  const ushort_* WnT_ws = wsu + WS_WNT;
  ushort_* S_ws = wsu + WS_S;
  float* rel_ws = (float*)((char*)wsu + WS_REL_BYTES);
  const int tid = threadIdx.x;

  for (int c = tid; c < 4096; c += 256) {  // stage W1pT (256 rows x 256B) swizzled
    int n = c >> 4, s = c & 15;
    uint4 src = *(const uint4*)(W1pT_ws + c * 8);
    *(uint4*)((char*)w1pt + n * 256 + ((s * 16) ^ ((n & 7) << 4))) = src;
  }

  const int w = tid >> 6, lane = tid & 63, l31 = lane & 31, h = lane >> 5, h8 = h * 8;
  const int mt = w & 1, ctb = (w >> 1) * 4, ctr = w >> 1;

  for (int tile = blockIdx.x; tile < 782; tile += gridDim.x) {
    const int pbase = tile * 64;
    for (int c = tid; c < 2048; c += 256) {  // stage feat cols 32..160 bf16 swizzled
      int row = c >> 5, c4 = c & 31;
      int p = pbase + row;
      uint2 d = {0u, 0u};
      if (p < NPTS) {
        if (F32) {
          float4 v = *(const float4*)((const float*)features + p * 160 + 32 + c4 * 4);
          d.x = cvtpk(v.x, v.y); d.y = cvtpk(v.z, v.w);
        } else {
          d = *(const uint2*)((const ushort_*)features + p * 160 + 32 + c4 * 4);
        }
      }
      *(uint2*)((char*)feats + row * 256 + ((c4 * 8) ^ ((row & 7) << 4))) = d;
    }
    __syncthreads();

    // ---- S GEMM: A = feat rows, B = W1p ----
    bf16x8s af[8];
    #pragma unroll
    for (int ks = 0; ks < 8; ++ks) {
      int row = mt * 32 + l31;
      af[ks] = *(const bf16x8s*)((const char*)feats + row * 256 +
                                 (((ks * 16 + h8) * 2) ^ ((row & 7) << 4)));
    }
    #pragma unroll
    for (int ci = 0; ci < 4; ++ci) {
      int ct = ctb + ci;
      float b1v = ldv<F32>(b1, ct * 32 + l31);
      f32x16 acc;
      #pragma unroll
      for (int r = 0; r < 16; ++r) acc[r] = b1v;
      #pragma unroll
      for (int ks = 0; ks < 8; ++ks) {
        int n = ct * 32 + l31;
        bf16x8s bf = *(const bf16x8s*)((const char*)w1pt + n * 256 +
                                       (((ks * 16 + h8) * 2) ^ ((n & 7) << 4)));
        acc = MFMA(af[ks], bf, acc);
      }
      #pragma unroll
      for (int r = 0; r < 16; ++r) {
        int p = pbase + mt * 32 + CROW(r, h);
        // S4 quad-interleaved: [p>>2][chan][p&3]
        if (p < NPTS)
          S_ws[(p >> 2) * 1024 + (ct * 32 + l31) * 4 + (p & 3)] = f2b(acc[r]);
      }
    }

    // ---- rel GEMM: A = pf (feat cols 0..32), B = Wn ----
    {
      int pm = pbase + mt * 32 + l31;
      pm = pm < NPTS ? pm : NPTS - 1;
      bf16x8s ar[2];
      #pragma unroll
      for (int ks = 0; ks < 2; ++ks) {
        F8 v = ld8<F32>(features, pm * 160 + ks * 16 + h8);
        ar[ks] = pack8(v);
      }
      f32x16 acc;
      #pragma unroll
      for (int r = 0; r < 16; ++r) acc[r] = 0.f;
      #pragma unroll
      for (int ks = 0; ks < 2; ++ks) {
        int n = ctr * 32 + l31;
        FragU bw;
        bw.q = *(const uint4*)(WnT_ws + n * 32 + ks * 16 + h8);
        acc = MFMA(ar[ks], bw.v, acc);
      }
      int j = ctr * 32 + l31;
      if (j < 48) {
        float bnv = ldv<F32>(bn, j);
        int c = j - (j / 3) * 3;
        #pragma unroll
        for (int r = 0; r < 16; ++r) {
          int p = pbase + mt * 32 + CROW(r, h);
          if (p < NPTS) {
            float rv = acc[r] + bnv;
            rel_ws[p * 48 + j] = rv;
            out[(size_t)p * 48 + j] = ldv<F32>(points, p * 3 + c) + 0.25f * rv;
          }
        }
      }
    }
    __syncthreads();
  }
}

__global__ void __launch_bounds__(256, 2)
kS(const void* points, const void* features, const void* bn, const void* b1,
   ushort_* wsu, float* out) {
  __shared__ ushort_ w1pt[32768];  // 64KB
  __shared__ ushort_ feats[8192];  // 16KB
  if (sniff_f32(features))
    runS<true>(points, features, bn, b1, wsu, out, w1pt, feats);
  else
    runS<false>(points, features, bn, b1, wsu, out, w1pt, feats);
}

// ---------------- Kernel M ----------------
// assemble: C-layout acc (lane=m, reg->channel via CROW) -> B-frag (lane=m,
// regs = 8 consecutive channels), relu(x + bias). Verified layer3 path (R4).
__device__ __forceinline__ bf16x8s assemble_b(const f32x16& a, int base, bool lo,
                                              float bias) {
  float e[8];
  #pragma unroll
  for (int j = 0; j < 8; ++j) e[j] = relu_(a[base + j] + bias);
  uint_ A0 = cvtpk(e[0], e[1]), A1 = cvtpk(e[2], e[3]);
  uint_ B0 = cvtpk(e[4], e[5]), B1 = cvtpk(e[6], e[7]);
  uint_ sA0 = (uint_)__shfl_xor((int)A0, 32);
  uint_ sA1 = (uint_)__shfl_xor((int)A1, 32);
  uint_ sB0 = (uint_)__shfl_xor((int)B0, 32);
  uint_ sB1 = (uint_)__shfl_xor((int)B1, 32);
  FragU o;
  o.u[0] = lo ? A0 : sB0;
  o.u[1] = lo ? A1 : sB1;
  o.u[2] = lo ? sA0 : B0;
  o.u[3] = lo ? sA1 : B1;
  return o.v;
}
__device__ __forceinline__ bf16x8s assemble(const f32x16& a, int base, bool lo) {
  float e[8];
  #pragma unroll
  for (int j = 0; j < 8; ++j) e[j] = relu_(a[base + j]);
  uint_ A0 = cvtpk(e[0], e[1]), A1 = cvtpk(e[2], e[3]);
  uint_ B0 = cvtpk(e[4], e[5]), B1 = cvtpk(e[6], e[7]);
  uint_ sA0 = (uint_)__shfl_xor((int)A0, 32);
  uint_ sA1 = (uint_)__shfl_xor((int)A1, 32);
  uint_ sB0 = (uint_)__shfl_xor((int)B0, 32);
  uint_ sB1 = (uint_)__shfl_xor((int)B1, 32);
  FragU o;
  o.u[0] = lo ? A0 : sB0;
  o.u[1] = lo ? A1 : sB1;
  o.u[2] = lo ? sA0 : B0;
  o.u[3] = lo ? sA1 : B1;
  return o.v;
}

template<bool F32>
__device__ void runM(const void* W1, const void* b2, const void* b3,
                     const ushort_* wsu, float* out,
                     ushort_* w2t, ushort_* w3t, uint_* w1x, float* b2f, float* b3f) {
  const ushort_* S4 = wsu + WS_S;
  const float* rel_ws = (const float*)((const char*)wsu + WS_REL_BYTES);
  const int tid = threadIdx.x;

  for (int c = tid; c < 4608; c += 512) {
    if (c < 4096) {
      int n = c >> 5, s = c & 31;
      uint4 src = *(const uint4*)(wsu + WS_W2T + c * 8);
      *(uint4*)((char*)w2t + n * 512 + ((s * 16) ^ ((n & 7) << 4))) = src;
    } else {
      int c2 = c - 4096, n = c2 >> 4, s = c2 & 15;
      uint4 src = *(const uint4*)(wsu + WS_W3T + c2 * 8);
      *(uint4*)((char*)w3t + n * 256 + ((s * 16) ^ ((n & 7) << 4))) = src;
    }
  }
  if (tid < 256) {
    float w0 = ldv<F32>(W1, 0 * 256 + tid);
    float w1v = ldv<F32>(W1, 1 * 256 + tid);
    float w2v = ldv<F32>(W1, 2 * 256 + tid);
    w1x[tid * 2 + 0] = cvtpk(w0, w1v);
    w1x[tid * 2 + 1] = cvtpk(w2v, 0.f);   // hi 16 bits = 0 -> S packs into hi
  }
  if (tid < 128) b2f[tid] = ldv<F32>(b2, tid);
  if (tid < 32) b3f[tid] = ldv<F32>(b3, tid);
  __syncthreads();

  const int w = tid >> 6, lane = tid & 63, l31 = lane & 31, h = lane >> 5;
  const bool lo = lane < 32;
  const int slot = blockIdx.x * 8 + w;
  const int stride = gridDim.x * 8;

  // per-lane biases (loop-invariant registers)
  float b2v[4];
  #pragma unroll
  for (int mt = 0; mt < 4; ++mt) b2v[mt] = b2f[mt * 32 + l31];
  float4 b3v[4];
  #pragma unroll
  for (int q = 0; q < 4; ++q) b3v[q] = *(const float4*)(b3f + q * 8 + 4 * h);

  f32x16 zero16;
  #pragma unroll
  for (int r = 0; r < 16; ++r) zero16[r] = 0.f;

  for (int g = slot; g < 12500; g += stride) {
    const int p0 = g * 4;

    // Y-frags per tile t (points p0+2t, p0+2t+1): k0..2 = rel, k3=(m<16), k4=(m>=16)
    bf16x8s yf[2];
    #pragma unroll
    for (int t = 0; t < 2; ++t) {
      int p = p0 + 2 * t + (l31 >> 4);
      const float* rp = rel_ws + p * 48 + (l31 & 15) * 3;
      float r0 = rp[0], r1 = rp[1], r2 = rp[2];
      float selA = (l31 >> 4) ? 0.f : 1.f;
      float selB = 1.f - selA;
      FragU y;
      y.u[0] = h ? 0u : cvtpk(r0, r1);
      y.u[1] = h ? 0u : cvtpk(r2, selA);
      y.u[2] = h ? 0u : cvtpk(selB, 0.f);
      y.u[3] = 0u;
      yf[t] = y.v;
    }

    f32x16 accA[4], accB[4];

    #pragma unroll
    for (int grp = 0; grp < 8; ++grp) {
      const int c0 = grp * 32;
      // coalesced S quad: sq.x = S[p0]|S[p0+1]<<16, sq.y = S[p0+2]|S[p0+3]<<16
      uint2 sq = *(const uint2*)(S4 + (size_t)g * 1024 + (c0 + l31) * 4);
      uint2 wp = *(const uint2*)(w1x + (c0 + l31) * 2);
      FragU x0, x1;
      x0.u[0] = h ? 0u : wp.x;
      x0.u[1] = h ? 0u : (wp.y | (sq.x << 16));
      x0.u[2] = h ? 0u : (sq.x >> 16);
      x0.u[3] = 0u;
      x1.u[0] = h ? 0u : wp.x;
      x1.u[1] = h ? 0u : (wp.y | (sq.y << 16));
      x1.u[2] = h ? 0u : (sq.y >> 16);
      x1.u[3] = 0u;
      f32x16 acc10 = MFMA(x0.v, yf[0], zero16);
      f32x16 acc11 = MFMA(x1.v, yf[1], zero16);
      #pragma unroll
      for (int b = 0; b < 2; ++b) {
        bf16x8s hA = assemble(acc10, b * 8, lo);
        bf16x8s hB = assemble(acc11, b * 8, lo);
        const int kb = (c0 + b * 16 + h * 8) * 2;
        #pragma unroll
        for (int mt = 0; mt < 4; ++mt) {
          int n = mt * 32 + l31;
          bf16x8s af = *(const bf16x8s*)((const char*)w2t + n * 512 +
                                         (kb ^ ((n & 7) << 4)));
          if (grp == 0 && b == 0) {
            accA[mt] = MFMA(af, hA, zero16);
            accB[mt] = MFMA(af, hB, zero16);
          } else {
            accA[mt] = MFMA(af, hA, accA[mt]);
            accB[mt] = MFMA(af, hB, accB[mt]);
          }
        }
      }
    }

    // layer3: A = W3T (LDS), B = half-swapped relu(h2 + b2) from acc regs
    f32x16 o3A, o3B;
    #pragma unroll
    for (int ks3 = 0; ks3 < 8; ++ks3) {
      int kb = (ks3 * 16 + h * 8) * 2;
      bf16x8s a3 = *(const bf16x8s*)((const char*)w3t + l31 * 256 +
                                     (kb ^ ((l31 & 7) << 4)));
      const int mt = ks3 >> 1, base = (ks3 & 1) * 8;
      bf16x8s B3A = assemble_b(accA[mt], base, lo, b2v[mt]);
      bf16x8s B3B = assemble_b(accB[mt], base, lo, b2v[mt]);
      if (ks3 == 0) {
        o3A = MFMA(a3, B3A, zero16);
        o3B = MFMA(a3, B3B, zero16);
      } else {
        o3A = MFMA(a3, B3A, o3A);
        o3B = MFMA(a3, B3B, o3B);
      }
    }

    const size_t rowA = (size_t)p0 * 16 + l31;
    #pragma unroll
    for (int q = 0; q < 4; ++q) {
      float4 vA = {relu_(o3A[4 * q] + b3v[q].x), relu_(o3A[4 * q + 1] + b3v[q].y),
                   relu_(o3A[4 * q + 2] + b3v[q].z), relu_(o3A[4 * q + 3] + b3v[q].w)};
      float4 vB = {relu_(o3B[4 * q] + b3v[q].x), relu_(o3B[4 * q + 1] + b3v[q].y),
                   relu_(o3B[4 * q + 2] + b3v[q].z), relu_(o3B[4 * q + 3] + b3v[q].w)};
      *(float4*)(out + OFF_FC3 + rowA * 32 + q * 8 + 4 * h) = vA;
      *(float4*)(out + OFF_FC3 + (rowA + 32) * 32 + q * 8 + 4 * h) = vB;
    }
  }
}

__global__ void __launch_bounds__(512, 2)
kM(const void* features, const void* W1, const void* b2, const void* b3,
   const ushort_* wsu, float* out) {
  __shared__ ushort_ w2t[32768];  // 64KB swizzled
  __shared__ ushort_ w3t[4096];   // 8KB swizzled
  __shared__ uint_ w1x[512];      // 2KB: per n1 packed (W10,W11),(W12,0)
  __shared__ float b2f[128];
  __shared__ float b3f[32];
  if (sniff_f32(features))
    runM<true>(W1, b2, b3, wsu, out, w2t, w3t, w1x, b2f, b3f);
  else
    runM<false>(W1, b2, b3, wsu, out, w2t, w3t, w1x, b2f, b3f);
}

extern "C" void kernel_launch(void* const* d_in, const int* in_sizes, int n_in,
                              void* d_out, int out_size, void* d_ws, size_t ws_size,
                              hipStream_t stream) {
  const void* points   = d_in[0];
  const void* features = d_in[1];
  const void* batch    = d_in[2];
  const void* Wn = d_in[3];  const void* bn = d_in[4];
  const void* W1 = d_in[5];  const void* b1 = d_in[6];
  const void* W2 = d_in[7];  const void* b2 = d_in[8];
  const void* W3 = d_in[9];  const void* b3 = d_in[10];
  float* out = (float*)d_out;
  ushort_* wsu = (ushort_*)d_ws;

  hipLaunchKernelGGL(kT, dim3(512), dim3(256), 0, stream,
                     features, batch, W1, Wn, W2, W3, wsu, out);
  hipLaunchKernelGGL(kS, dim3(782), dim3(256), 0, stream,
                     points, features, bn, b1, wsu, out);
  hipLaunchKernelGGL(kM, dim3(512), dim3(512), 0, stream,
                     features, W1, b2, b3, wsu, out);
}